// Round 3
// baseline (876.280 us; speedup 1.0000x reference)
//
#include <hip/hip_runtime.h>

typedef _Float16 half8 __attribute__((ext_vector_type(8)));
typedef _Float16 half4 __attribute__((ext_vector_type(4)));
typedef float floatx4 __attribute__((ext_vector_type(4)));

// LDS layout helper: rows of 32 fp16 (one BK=32 slice), 4 chunks of 8, XOR-swizzled
// so ds_read_b128 fragment reads are ~conflict-free.
__device__ __forceinline__ int lds_off(int row, int chunk) {
    return row * 32 + ((chunk ^ (row & 3)) << 3);
}

__device__ __forceinline__ void ld16f(float* d, const float* s) {
    *(float4*)(d + 0)  = *(const float4*)(s + 0);
    *(float4*)(d + 4)  = *(const float4*)(s + 4);
    *(float4*)(d + 8)  = *(const float4*)(s + 8);
    *(float4*)(d + 12) = *(const float4*)(s + 12);
}

__device__ __forceinline__ void cvt16(half8& h0, half8& h1, const float* f) {
#pragma unroll
    for (int i = 0; i < 8; i++) { h0[i] = (_Float16)f[i]; h1[i] = (_Float16)f[8 + i]; }
}

// Fused Q/K/V projections. C = A @ W^T + b, A fp32 [4096,1024], W fp32 [1024,1024].
// 128x128 tile, BK=32, ping-pong double-buffered LDS: ONE barrier per K-step,
// global prefetch runs a full iteration ahead (T3 2-phase).
// Grid: x = tileM (32), y = tileN (8), z = matrix  -> blocks sharing an A-panel
// have ids congruent mod 8 => same XCD (T1 L2 locality).
// z=0 -> Q (head-split [bh][l][d]), z=1 -> K (same), z=2 -> V transposed [bh][d][l].
__global__ __launch_bounds__(256) void gemm_qkv(
    const float* __restrict__ q, const float* __restrict__ k, const float* __restrict__ v,
    const float* __restrict__ Wq, const float* __restrict__ Wk, const float* __restrict__ Wv,
    const float* __restrict__ bq, const float* __restrict__ bk, const float* __restrict__ bv,
    _Float16* __restrict__ outQ, _Float16* __restrict__ outK, _Float16* __restrict__ outVt)
{
    __shared__ __align__(16) _Float16 sA[2][128 * 32];
    __shared__ __align__(16) _Float16 sB[2][128 * 32];

    const int t = threadIdx.x;
    const int tileM = blockIdx.x * 128;
    const int tileN = blockIdx.y * 128;
    const int z = blockIdx.z;

    const float* Ab = (z == 0) ? q : (z == 1 ? k : v);
    const float* Bb = (z == 0) ? Wq : (z == 1 ? Wk : Wv);
    const float* bias = (z == 0) ? bq : (z == 1 ? bk : bv);

    const int srow = t >> 1, shalf = t & 1, c0 = shalf * 2;
    const int lane = t & 63, wave = t >> 6;
    const int wm = (wave >> 1) * 64, wn = (wave & 1) * 64;
    const int l15 = lane & 15, quad = lane >> 4;

    const float* Arow = Ab + (long)(tileM + srow) * 1024 + shalf * 16;
    const float* Brow = Bb + (long)(tileN + srow) * 1024 + shalf * 16;

    float fA[16], fB[16];
    ld16f(fA, Arow);
    ld16f(fB, Brow);
    {   // stage tile 0 into buffer 0
        half8 h0, h1;
        cvt16(h0, h1, fA);
        *(half8*)&sA[0][lds_off(srow, c0)]     = h0;
        *(half8*)&sA[0][lds_off(srow, c0 + 1)] = h1;
        cvt16(h0, h1, fB);
        *(half8*)&sB[0][lds_off(srow, c0)]     = h0;
        *(half8*)&sB[0][lds_off(srow, c0 + 1)] = h1;
    }
    ld16f(fA, Arow + 32);   // prefetch tile 1
    ld16f(fB, Brow + 32);
    __syncthreads();

    floatx4 acc[4][4];
#pragma unroll
    for (int i = 0; i < 4; i++)
#pragma unroll
        for (int j = 0; j < 4; j++)
            acc[i][j] = (floatx4){0.f, 0.f, 0.f, 0.f};

    for (int it = 0; it < 32; ++it) {
        const int cur = it & 1;
        half8 af[4], bf[4];
#pragma unroll
        for (int i = 0; i < 4; i++) af[i] = *(const half8*)&sA[cur][lds_off(wm + i * 16 + l15, quad)];
#pragma unroll
        for (int j = 0; j < 4; j++) bf[j] = *(const half8*)&sB[cur][lds_off(wn + j * 16 + l15, quad)];
        if (it + 1 < 32) {   // stage prefetched tile into the other buffer
            half8 h0, h1;
            cvt16(h0, h1, fA);
            *(half8*)&sA[cur ^ 1][lds_off(srow, c0)]     = h0;
            *(half8*)&sA[cur ^ 1][lds_off(srow, c0 + 1)] = h1;
            cvt16(h0, h1, fB);
            *(half8*)&sB[cur ^ 1][lds_off(srow, c0)]     = h0;
            *(half8*)&sB[cur ^ 1][lds_off(srow, c0 + 1)] = h1;
        }
        if (it + 2 < 32) {   // prefetch the tile after that
            ld16f(fA, Arow + (it + 2) * 32);
            ld16f(fB, Brow + (it + 2) * 32);
        }
#pragma unroll
        for (int i = 0; i < 4; i++)
#pragma unroll
            for (int j = 0; j < 4; j++)
                acc[i][j] = __builtin_amdgcn_mfma_f32_16x16x32_f16(af[i], bf[j], acc[i][j], 0, 0, 0);
        __syncthreads();
    }

    // ---- epilogue ----
#pragma unroll
    for (int i = 0; i < 4; i++) {
#pragma unroll
        for (int j = 0; j < 4; j++) {
            const int row0 = tileM + wm + i * 16 + quad * 4;
            const int col  = tileN + wn + j * 16 + l15;
            if (z == 2) {
                half4 hv;
#pragma unroll
                for (int r = 0; r < 4; r++) hv[r] = (_Float16)(acc[i][j][r] + bias[col]);
                const int bh = ((row0 >> 11) << 4) + (col >> 6);
                *(half4*)&outVt[(long)bh * 131072 + (long)(col & 63) * 2048 + (row0 & 2047)] = hv;
            } else {
                _Float16* dst = z ? outK : outQ;
#pragma unroll
                for (int r = 0; r < 4; r++) {
                    const int row = row0 + r;
                    dst[(long)(((row >> 11) << 4) + (col >> 6)) * 131072 + (long)(row & 2047) * 64 + (col & 63)] =
                        (_Float16)(acc[i][j][r] + bias[col]);
                }
            }
        }
    }
}

// Output projection: C = A @ B^T + bias, A fp16 [4096,1024], B fp32 [1024,1024],
// C fp32 [4096,1024]. Same ping-pong single-barrier structure.
__global__ __launch_bounds__(256) void gemm_out(
    const _Float16* __restrict__ A, const float* __restrict__ B,
    const float* __restrict__ bias, float* __restrict__ C)
{
    __shared__ __align__(16) _Float16 sA[2][128 * 32];
    __shared__ __align__(16) _Float16 sB[2][128 * 32];

    const int t = threadIdx.x;
    const int tileM = blockIdx.x * 128;
    const int tileN = blockIdx.y * 128;

    const int srow = t >> 1, shalf = t & 1, c0 = shalf * 2;
    const int lane = t & 63, wave = t >> 6;
    const int wm = (wave >> 1) * 64, wn = (wave & 1) * 64;
    const int l15 = lane & 15, quad = lane >> 4;

    const _Float16* Arow = A + (long)(tileM + srow) * 1024 + shalf * 16;
    const float*    Brow = B + (long)(tileN + srow) * 1024 + shalf * 16;

    half8 hA[2];
    float fB[16];
    hA[0] = *(const half8*)Arow;
    hA[1] = *(const half8*)(Arow + 8);
    ld16f(fB, Brow);
    {
        *(half8*)&sA[0][lds_off(srow, c0)]     = hA[0];
        *(half8*)&sA[0][lds_off(srow, c0 + 1)] = hA[1];
        half8 h0, h1;
        cvt16(h0, h1, fB);
        *(half8*)&sB[0][lds_off(srow, c0)]     = h0;
        *(half8*)&sB[0][lds_off(srow, c0 + 1)] = h1;
    }
    hA[0] = *(const half8*)(Arow + 32);
    hA[1] = *(const half8*)(Arow + 40);
    ld16f(fB, Brow + 32);
    __syncthreads();

    floatx4 acc[4][4];
#pragma unroll
    for (int i = 0; i < 4; i++)
#pragma unroll
        for (int j = 0; j < 4; j++)
            acc[i][j] = (floatx4){0.f, 0.f, 0.f, 0.f};

    for (int it = 0; it < 32; ++it) {
        const int cur = it & 1;
        half8 af[4], bf[4];
#pragma unroll
        for (int i = 0; i < 4; i++) af[i] = *(const half8*)&sA[cur][lds_off(wm + i * 16 + l15, quad)];
#pragma unroll
        for (int j = 0; j < 4; j++) bf[j] = *(const half8*)&sB[cur][lds_off(wn + j * 16 + l15, quad)];
        if (it + 1 < 32) {
            *(half8*)&sA[cur ^ 1][lds_off(srow, c0)]     = hA[0];
            *(half8*)&sA[cur ^ 1][lds_off(srow, c0 + 1)] = hA[1];
            half8 h0, h1;
            cvt16(h0, h1, fB);
            *(half8*)&sB[cur ^ 1][lds_off(srow, c0)]     = h0;
            *(half8*)&sB[cur ^ 1][lds_off(srow, c0 + 1)] = h1;
        }
        if (it + 2 < 32) {
            const int k2 = (it + 2) << 5;
            hA[0] = *(const half8*)(Arow + k2);
            hA[1] = *(const half8*)(Arow + k2 + 8);
            ld16f(fB, Brow + k2);
        }
#pragma unroll
        for (int i = 0; i < 4; i++)
#pragma unroll
            for (int j = 0; j < 4; j++)
                acc[i][j] = __builtin_amdgcn_mfma_f32_16x16x32_f16(af[i], bf[j], acc[i][j], 0, 0, 0);
        __syncthreads();
    }

#pragma unroll
    for (int i = 0; i < 4; i++)
#pragma unroll
        for (int j = 0; j < 4; j++)
#pragma unroll
            for (int r = 0; r < 4; r++) {
                const int row = tileM + wm + i * 16 + quad * 4 + r;
                const int col = tileN + wn + j * 16 + l15;
                C[(long)row * 1024 + col] = acc[i][j][r] + bias[col];
            }
}

// Fused attention: per (b,h) and 128-query-row block, two-pass flash-style.
// LDS aliasing: after QK^T reads sK, waves 0/1 reuse the sK region for their
// wave-private P tiles (sP is write/read by the same wave only -> no extra
// barrier). 48 KB total -> 3 blocks/CU. Grid: x = bh (32), y = tileM (16) so
// blocks sharing a (b,h) K/V slice land on the same XCD.
__global__ __launch_bounds__(256, 3) void attn_fused(
    const _Float16* __restrict__ Q,   // [32][2048][64]
    const _Float16* __restrict__ K,   // [32][2048][64]
    const _Float16* __restrict__ Vt,  // [32][64][2048]
    float* __restrict__ W,            // [32][2048][2048] (weights output)
    _Float16* __restrict__ Z)         // [4096][1024]  (b,l,h,d)
{
    __shared__ __align__(16) _Float16 S[24576];   // 48 KB
    _Float16* sK = S;                              // [128 key][64 d]   (16 KB)
    _Float16* sV = S + 8192;                       // [64 d][128 key]   (16 KB)
    // per-wave P tile (32 q rows x 128 keys, 8 KB): waves 0/1 alias the sK
    // region (dead after QK^T), waves 2/3 use the extra 16 KB.

    const int t = threadIdx.x;
    const int bh = blockIdx.x;
    const int tileM = blockIdx.y * 128;
    const int lane = t & 63, wave = t >> 6;
    const int l15 = lane & 15, quad = lane >> 4;
    const int wm = wave * 32;
    _Float16* myP = (wave < 2) ? (S + wave * 4096) : (S + 16384 + (wave - 2) * 4096);

    const _Float16* Qb = Q + (long)bh * 131072;
    const _Float16* Kb = K + (long)bh * 131072;
    const _Float16* Vb = Vt + (long)bh * 131072;
    float* Wb = W + (long)bh * 4194304;

    const int krow = t >> 1, khalf = t & 1;   // K staging: 2 threads/row
    const int vrow = t >> 2, vq = t & 3;      // V staging: 4 threads/row

    // Q fragments (persistent): lane holds Q[row=wm+i*16+l15][k=kk*32+quad*8+e]
    half8 qf[2][2];
#pragma unroll
    for (int i = 0; i < 2; i++)
#pragma unroll
        for (int kk = 0; kk < 2; kk++)
            qf[i][kk] = *(const half8*)(Qb + (long)(tileM + wm + i * 16 + l15) * 64 + kk * 32 + quad * 8);

    float m[2][4], l[2][4];
#pragma unroll
    for (int i = 0; i < 2; i++)
#pragma unroll
        for (int r = 0; r < 4; r++) { m[i][r] = -__builtin_inff(); l[i][r] = 0.f; }

    const _Float16* Ksrc = Kb + (long)krow * 64 + khalf * 32;
    const _Float16* Vsrc = Vb + (long)vrow * 2048;

    half8 kr[4];
#pragma unroll
    for (int c = 0; c < 4; c++) kr[c] = *(const half8*)(Ksrc + c * 8);

    // ---------------- pass 1: row stats ----------------
    for (int kv = 0; kv < 2048; kv += 128) {
        __syncthreads();
#pragma unroll
        for (int c = 0; c < 4; c++)
            *(half8*)&sK[krow * 64 + (((khalf * 4 + c) ^ (krow & 7)) << 3)] = kr[c];
        __syncthreads();
        if (kv + 128 < 2048) {
#pragma unroll
            for (int c = 0; c < 4; c++) kr[c] = *(const half8*)(Ksrc + (long)(kv + 128) * 64 + c * 8);
        }

        floatx4 acc[2][8];
#pragma unroll
        for (int i = 0; i < 2; i++)
#pragma unroll
            for (int j = 0; j < 8; j++) acc[i][j] = (floatx4){0.f, 0.f, 0.f, 0.f};

#pragma unroll
        for (int kk = 0; kk < 2; kk++) {
#pragma unroll
            for (int j = 0; j < 8; j++) {
                const int row = j * 16 + l15;
                half8 bf = *(const half8*)&sK[row * 64 + (((kk * 4 + quad) ^ (row & 7)) << 3)];
                acc[0][j] = __builtin_amdgcn_mfma_f32_16x16x32_f16(qf[0][kk], bf, acc[0][j], 0, 0, 0);
                acc[1][j] = __builtin_amdgcn_mfma_f32_16x16x32_f16(qf[1][kk], bf, acc[1][j], 0, 0, 0);
            }
        }

#pragma unroll
        for (int i = 0; i < 2; i++)
#pragma unroll
            for (int r = 0; r < 4; r++) {
                float tmax = acc[i][0][r];
#pragma unroll
                for (int j = 1; j < 8; j++) tmax = fmaxf(tmax, acc[i][j][r]);
#pragma unroll
                for (int off = 1; off < 16; off <<= 1) tmax = fmaxf(tmax, __shfl_xor(tmax, off));
                const float mn = fmaxf(m[i][r], tmax * 0.125f);
                const float corr = __expf(m[i][r] - mn);
                float ts = 0.f;
#pragma unroll
                for (int j = 0; j < 8; j++) ts += __expf(acc[i][j][r] * 0.125f - mn);
#pragma unroll
                for (int off = 1; off < 16; off <<= 1) ts += __shfl_xor(ts, off);
                l[i][r] = l[i][r] * corr + ts;
                m[i][r] = mn;
            }
    }

    // invert sums once
#pragma unroll
    for (int i = 0; i < 2; i++)
#pragma unroll
        for (int r = 0; r < 4; r++) l[i][r] = 1.f / l[i][r];

    floatx4 accz[2][4];
#pragma unroll
    for (int i = 0; i < 2; i++)
#pragma unroll
        for (int j = 0; j < 4; j++) accz[i][j] = (floatx4){0.f, 0.f, 0.f, 0.f};

    // reload K and V tiles for kv = 0
#pragma unroll
    for (int c = 0; c < 4; c++) kr[c] = *(const half8*)(Ksrc + c * 8);
    half8 vr[4];
#pragma unroll
    for (int c = 0; c < 4; c++) vr[c] = *(const half8*)(Vsrc + (vq + c * 4) * 8);

    // ---------------- pass 2: P write + PV ----------------
    for (int kv = 0; kv < 2048; kv += 128) {
        __syncthreads();   // prior PV reads (sV + per-wave sP) done; restage
#pragma unroll
        for (int c = 0; c < 4; c++)
            *(half8*)&sK[krow * 64 + (((khalf * 4 + c) ^ (krow & 7)) << 3)] = kr[c];
#pragma unroll
        for (int c = 0; c < 4; c++) {
            const int ch = vq + c * 4;
            *(half8*)&sV[vrow * 128 + ((ch ^ (vrow & 15)) << 3)] = vr[c];
        }
        __syncthreads();
        if (kv + 128 < 2048) {
#pragma unroll
            for (int c = 0; c < 4; c++) kr[c] = *(const half8*)(Ksrc + (long)(kv + 128) * 64 + c * 8);
        }

        floatx4 acc[2][8];
#pragma unroll
        for (int i = 0; i < 2; i++)
#pragma unroll
            for (int j = 0; j < 8; j++) acc[i][j] = (floatx4){0.f, 0.f, 0.f, 0.f};

#pragma unroll
        for (int kk = 0; kk < 2; kk++) {
#pragma unroll
            for (int j = 0; j < 8; j++) {
                const int row = j * 16 + l15;
                half8 bf = *(const half8*)&sK[row * 64 + (((kk * 4 + quad) ^ (row & 7)) << 3)];
                acc[0][j] = __builtin_amdgcn_mfma_f32_16x16x32_f16(qf[0][kk], bf, acc[0][j], 0, 0, 0);
                acc[1][j] = __builtin_amdgcn_mfma_f32_16x16x32_f16(qf[1][kk], bf, acc[1][j], 0, 0, 0);
            }
        }
        __syncthreads();   // all waves done reading sK; waves 0/1 overwrite it with sP

        // normalize, write weights (fp32, exactly once), stash fp16 P into own sP
#pragma unroll
        for (int i = 0; i < 2; i++) {
#pragma unroll
            for (int r = 0; r < 4; r++) {
                const int ql = i * 16 + quad * 4 + r;          // local q row in [0,32)
                float* wr = Wb + (long)(tileM + wm + ql) * 2048 + kv + l15;
                _Float16* sprow = myP + ql * 128 + (l15 & 7);
                const int qx = ql & 15;
                const int hi = l15 >> 3;
#pragma unroll
                for (int j = 0; j < 8; j++) {
                    const float p = __expf(acc[i][j][r] * 0.125f - m[i][r]) * l[i][r];
                    __builtin_nontemporal_store(p, wr + j * 16);
                    sprow[((j * 2 + hi) ^ qx) << 3] = (_Float16)p;
                }
            }
        }

        // Z += P @ Vt^T  (no barrier: myP is wave-private, sV untouched)
#pragma unroll
        for (int kk = 0; kk < 4; kk++) {
            half8 pf[2];
#pragma unroll
            for (int i = 0; i < 2; i++) {
                const int ql = i * 16 + l15;
                pf[i] = *(const half8*)&myP[ql * 128 + (((kk * 4 + quad) ^ (ql & 15)) << 3)];
            }
#pragma unroll
            for (int j = 0; j < 4; j++) {
                const int d = j * 16 + l15;
                half8 vf = *(const half8*)&sV[d * 128 + (((kk * 4 + quad) ^ (d & 15)) << 3)];
                accz[0][j] = __builtin_amdgcn_mfma_f32_16x16x32_f16(pf[0], vf, accz[0][j], 0, 0, 0);
                accz[1][j] = __builtin_amdgcn_mfma_f32_16x16x32_f16(pf[1], vf, accz[1][j], 0, 0, 0);
            }
        }

        if (kv + 128 < 2048) {   // V prefetch at loop bottom (short live range)
#pragma unroll
            for (int c = 0; c < 4; c++) vr[c] = *(const half8*)(Vsrc + kv + 128 + (vq + c * 4) * 8);
        }
    }

    // ---- epilogue: Z to fp16 workspace [b*2048+l][h*64+d] ----
    const int bb = bh >> 4, hd = bh & 15;
#pragma unroll
    for (int i = 0; i < 2; i++)
#pragma unroll
        for (int j = 0; j < 4; j++)
#pragma unroll
            for (int r = 0; r < 4; r++)
                Z[(long)(bb * 2048 + tileM + wm + i * 16 + quad * 4 + r) * 1024 + hd * 64 + j * 16 + l15] =
                    (_Float16)accz[i][j][r];
}

extern "C" void kernel_launch(void* const* d_in, const int* in_sizes, int n_in,
                              void* d_out, int out_size, void* d_ws, size_t ws_size,
                              hipStream_t stream) {
    (void)in_sizes; (void)n_in; (void)out_size; (void)ws_size;
    const float* query = (const float*)d_in[0];
    const float* key   = (const float*)d_in[1];
    const float* value = (const float*)d_in[2];
    const float* Wq = (const float*)d_in[3];
    const float* bq = (const float*)d_in[4];
    const float* Wk = (const float*)d_in[5];
    const float* bk = (const float*)d_in[6];
    const float* Wv = (const float*)d_in[7];
    const float* bv = (const float*)d_in[8];
    const float* Wo = (const float*)d_in[9];
    const float* bo = (const float*)d_in[10];

    _Float16* wsQ  = (_Float16*)d_ws;        // [32][2048][64]
    _Float16* wsK  = wsQ + 4194304;          // [32][2048][64]
    _Float16* wsVt = wsK + 4194304;          // [32][64][2048]
    _Float16* wsZ  = wsVt + 4194304;         // [4096][1024]

    float* outF = (float*)d_out;             // [4096][1024]
    float* Wgt  = outF + 4194304;            // [32][2048][2048]

    dim3 blk(256);
    // Q/K/V projections (x = tileM so A-panel sharers stay on one XCD)
    gemm_qkv<<<dim3(32, 8, 3), blk, 0, stream>>>(query, key, value, Wq, Wk, Wv, bq, bk, bv, wsQ, wsK, wsVt);
    // Fused scores + softmax + AV (x = bh so K/V sharers stay on one XCD)
    attn_fused<<<dim3(32, 16), blk, 0, stream>>>(wsQ, wsK, wsVt, Wgt, wsZ);
    // out = Z Wo^T + bo
    gemm_out<<<dim3(32, 8), blk, 0, stream>>>(wsZ, Wo, bo, outF);
}